// Round 10
// baseline (992.280 us; speedup 1.0000x reference)
//
#include <hip/hip_runtime.h>
#include <hip/hip_bf16.h>

typedef __hip_bfloat16 bf16;
typedef __bf16 bf16x8 __attribute__((ext_vector_type(8)));
typedef float f32x4 __attribute__((ext_vector_type(4)));
typedef unsigned short u16;
typedef unsigned int u32;

#define SEQ 512
#define DMODEL 1024
#define FFDIM 4096
#define NHEAD 16
#define HDIM 64
#define NB 4
#define NLAYER 8

#define SBAR() asm volatile("s_barrier" ::: "memory")

__device__ __forceinline__ u16 f2bu(float f) {
    union { bf16 h; u16 u; } c; c.h = __float2bfloat16(f); return c.u;
}
__device__ __forceinline__ float bu2f(u16 u) {
    union { u32 i; float f; } c; c.i = ((u32)u) << 16; return c.f;
}

// async global->LDS, 16B per lane. LDS dest must be linear in lane order.
__device__ __forceinline__ void gload16(const bf16* g, bf16* l) {
    __builtin_amdgcn_global_load_lds(
        (const __attribute__((address_space(1))) unsigned int*)g,
        (__attribute__((address_space(3))) unsigned int*)l,
        16, 0, 0);
}

// ---------------------------------------------------------------------------
// Deep-pipelined NT GEMM core: 256(M) x 128(N) tile, BK=64, 512 threads
// (8 waves, 2Mx4N). Double-buffered LDS, counted vmcnt(6), st_16x32 swizzle
// via inverse-swizzled global source + swizzled ds_read. Fragments for the
// whole K-tile are hoisted to registers; stage loads issue BEFORE the MFMA
// cluster so they fly under compute.
// ---------------------------------------------------------------------------
__device__ __forceinline__ void gemm_pipe(
    const bf16* __restrict__ A, int lda,
    const bf16* __restrict__ B, int ldb,
    int nkt,
    f32x4 (&acc)[8][2],
    char* lA, char* lB)         // lA: 2 x 32KB, lB: 2 x 16KB
{
    const int tid = threadIdx.x;
    const int lane = tid & 63;
    const int wave = tid >> 6;
    const int wr = wave >> 2, wc = wave & 3;
    const int l15 = lane & 15, l4 = lane >> 4;

    auto stage = [&](int c, int t) {
        const bf16* Ak = A + t * 64;
        const bf16* Bk = B + t * 64;
        bf16* dA = (bf16*)(lA + c * 32768);
        bf16* dB = (bf16*)(lB + c * 16384);
#pragma unroll
        for (int it = 0; it < 4; ++it) {
            const int e = (it * 512 + tid) * 8;
            const int r = e >> 6;
            const int cb = (e & 63) * 2;
            const int sc = (cb ^ (((r >> 2) & 1) << 5)) >> 1;
            gload16(Ak + (long)r * lda + sc, dA + e);
        }
#pragma unroll
        for (int it = 0; it < 2; ++it) {
            const int e = (it * 512 + tid) * 8;
            const int r = e >> 6;
            const int cb = (e & 63) * 2;
            const int sc = (cb ^ (((r >> 2) & 1) << 5)) >> 1;
            gload16(Bk + (long)r * ldb + sc, dB + e);
        }
    };

    stage(0, 0);
    stage(1, 1);
    asm volatile("s_waitcnt vmcnt(6)" ::: "memory");
    SBAR();

    for (int t = 0; t < nkt; ++t) {
        const int cur = t & 1;
        const char* bA = lA + cur * 32768;
        const char* bB = lB + cur * 16384;

        bf16x8 bf_[2][2], af[8][2];
#pragma unroll
        for (int fn = 0; fn < 2; ++fn)
#pragma unroll
            for (int ks = 0; ks < 2; ++ks) {
                const int row = wc * 32 + fn * 16 + l15;
                int byte = row * 128 + (ks * 32 + l4 * 8) * 2;
                byte ^= ((row >> 2) & 1) << 5;
                bf_[fn][ks] = *(const bf16x8*)(bB + byte);
            }
#pragma unroll
        for (int i = 0; i < 8; ++i)
#pragma unroll
            for (int ks = 0; ks < 2; ++ks) {
                const int row = wr * 128 + i * 16 + l15;
                int byte = row * 128 + (ks * 32 + l4 * 8) * 2;
                byte ^= ((row >> 2) & 1) << 5;
                af[i][ks] = *(const bf16x8*)(bA + byte);
            }
        // my fragment reads must be complete before anyone overwrites buf[cur]
        asm volatile("s_waitcnt lgkmcnt(0)" ::: "memory");
        __builtin_amdgcn_sched_barrier(0);
        SBAR();                     // all waves done reading buf[cur]
        if (t + 2 < nkt) stage(cur, t + 2);   // async loads fly under MFMA

        __builtin_amdgcn_s_setprio(1);
#pragma unroll
        for (int i = 0; i < 8; ++i)
#pragma unroll
            for (int fn = 0; fn < 2; ++fn)
#pragma unroll
                for (int ks = 0; ks < 2; ++ks)
                    acc[i][fn] = __builtin_amdgcn_mfma_f32_16x16x32_bf16(
                        af[i][ks], bf_[fn][ks], acc[i][fn], 0, 0, 0);
        __builtin_amdgcn_s_setprio(0);

        if (t + 2 < nkt) {
            asm volatile("s_waitcnt vmcnt(6)" ::: "memory");  // tile t+1 landed
        } else {
            asm volatile("s_waitcnt vmcnt(0)" ::: "memory");
        }
        SBAR();
    }
}

// ---------------------------------------------------------------------------
// LayerNorm: in (fp32, row of 1024) -> out bf16; optional passthrough copy
// of the input row to hcopy (fuses the h=x init).
// ---------------------------------------------------------------------------
__global__ __launch_bounds__(256) void k_ln(const float* __restrict__ h,
                                            const float* __restrict__ w,
                                            const float* __restrict__ bp,
                                            bf16* __restrict__ out,
                                            float* __restrict__ hcopy)
{
    const int row = blockIdx.x;
    const int tid = threadIdx.x;
    const float4 x = ((const float4*)(h + (long)row * DMODEL))[tid];
    if (hcopy) ((float4*)(hcopy + (long)row * DMODEL))[tid] = x;
    float s  = x.x + x.y + x.z + x.w;
    float s2 = x.x * x.x + x.y * x.y + x.z * x.z + x.w * x.w;
#pragma unroll
    for (int off = 32; off; off >>= 1) { s += __shfl_xor(s, off); s2 += __shfl_xor(s2, off); }
    __shared__ float rs[4], rs2[4];
    const int wave = tid >> 6;
    if ((tid & 63) == 0) { rs[wave] = s; rs2[wave] = s2; }
    __syncthreads();
    const float S1 = rs[0] + rs[1] + rs[2] + rs[3];
    const float S2 = rs2[0] + rs2[1] + rs2[2] + rs2[3];
    const float mean = S1 * (1.0f / DMODEL);
    const float var  = S2 * (1.0f / DMODEL) - mean * mean;
    const float rstd = rsqrtf(var + 1e-5f);
    const float4 wv = ((const float4*)w)[tid];
    const float4 bv = ((const float4*)bp)[tid];
    uint2 o;
    o.x = (u32)f2bu((x.x - mean) * rstd * wv.x + bv.x) |
          ((u32)f2bu((x.y - mean) * rstd * wv.y + bv.y) << 16);
    o.y = (u32)f2bu((x.z - mean) * rstd * wv.z + bv.z) |
          ((u32)f2bu((x.w - mean) * rstd * wv.w + bv.w) << 16);
    ((uint2*)(out + (long)row * DMODEL))[tid] = o;
}

// ---------------------------------------------------------------------------
// All-layer weight transpose (r8 register version, zero LDS).
// Bound ~2.5 TB/s by scatter granularity; accepted.
// ---------------------------------------------------------------------------
__global__ __launch_bounds__(256) void k_transw_all(const float* __restrict__ w1,
                                                    const float* __restrict__ w2,
                                                    bf16* __restrict__ w1t,
                                                    bf16* __restrict__ w2t)
{
    int bid = blockIdx.x;
    const int l = bid >> 11;
    bid &= 2047;
    const long lofs = (long)l * DMODEL * FFDIM;
    const float* src; bf16* dst; int R, C, rb, cb;
    if (bid < 1024) {
        src = w1 + lofs; dst = w1t + lofs; R = DMODEL; C = FFDIM;
        rb = (bid >> 6) << 6; cb = (bid & 63) << 6;
    } else {
        bid -= 1024;
        src = w2 + lofs; dst = w2t + lofs; R = FFDIM; C = DMODEL;
        rb = (bid >> 4) << 6; cb = (bid & 15) << 6;
    }
    const int tid = threadIdx.x;
    const int lane = tid & 63, wave = tid >> 6;
    const int r0 = ((wave & 1) << 5) + ((lane >> 3) << 2);
    const int c0 = ((wave >> 1) << 5) + ((lane & 7) << 2);

    float4 v[4];
#pragma unroll
    for (int i = 0; i < 4; ++i)
        v[i] = *(const float4*)(src + (long)(rb + r0 + i) * C + cb + c0);
#pragma unroll
    for (int j = 0; j < 4; ++j) {
        const float a0 = (&v[0].x)[j], a1 = (&v[1].x)[j];
        const float a2 = (&v[2].x)[j], a3 = (&v[3].x)[j];
        uint2 o;
        o.x = (u32)f2bu(a0) | ((u32)f2bu(a1) << 16);
        o.y = (u32)f2bu(a2) | ((u32)f2bu(a3) << 16);
        *(uint2*)(dst + (long)(cb + c0 + j) * R + rb + r0) = o;
    }
}

// ---------------------------------------------------------------------------
// Merged QKV with in-flight fp32->bf16 weight conversion. grid (4, B*H).
// q scaled 1/8; v stored transposed vt[e][s].
// ---------------------------------------------------------------------------
__global__ __launch_bounds__(256) void k_qkv2(const bf16* __restrict__ y,
                                              const float* __restrict__ qwl,
                                              const float* __restrict__ kwl,
                                              const float* __restrict__ vwl,
                                              const float* __restrict__ qb,
                                              const float* __restrict__ kb,
                                              const float* __restrict__ vb,
                                              bf16* __restrict__ qh,
                                              bf16* __restrict__ kh,
                                              bf16* __restrict__ vt)
{
    __shared__ __align__(16) char lmem[128 * 64 * 2 + 64 * 64 * 2];  // lA 16KB + lB 8KB
    bf16* lA = (bf16*)lmem;
    char* lBb = lmem + 128 * 64 * 2;

    const int tid = threadIdx.x;
    const int lane = tid & 63, wave = tid >> 6;
    const int l15 = lane & 15, l4 = lane >> 4;
    const int z = blockIdx.y;
    const int b = z >> 4, hd = z & 15;
    const bf16* A = y + (long)b * SEQ * DMODEL + hd * HDIM + (long)blockIdx.x * 128 * DMODEL;

#pragma unroll
    for (int it = 0; it < 4; ++it) {
        const int f = (it * 256 + tid) * 8;
        const int r = f >> 6, c = f & 63;
        gload16(A + (long)r * DMODEL + c, lA + f);
    }
    __syncthreads();

    bf16x8 qa[2][2];
#pragma unroll
    for (int fm = 0; fm < 2; ++fm)
#pragma unroll
        for (int ks = 0; ks < 2; ++ks)
            qa[fm][ks] = *(const bf16x8*)(lA + (wave * 32 + fm * 16 + l15) * 64 + ks * 32 + l4 * 8);

    for (int t = 0; t < 3; ++t) {
        __syncthreads();
        const float* Bsrc = ((t == 0) ? qwl : (t == 1) ? kwl : vwl) + (long)hd * HDIM * HDIM;
#pragma unroll
        for (int it = 0; it < 4; ++it) {
            const int f = (it * 256 + tid) * 4;
            const float4 v = *(const float4*)(Bsrc + f);
            uint2 o;
            o.x = (u32)f2bu(v.x) | ((u32)f2bu(v.y) << 16);
            o.y = (u32)f2bu(v.z) | ((u32)f2bu(v.w) << 16);
            const int row = f >> 6;
            const int byte = (f << 1) ^ ((row & 7) << 4);
            *(uint2*)(lBb + byte) = o;
        }
        __syncthreads();

        bf16x8 bfr[4][2];
#pragma unroll
        for (int fn = 0; fn < 4; ++fn)
#pragma unroll
            for (int ks = 0; ks < 2; ++ks) {
                const int row = fn * 16 + l15;
                int byte = (row << 7) + ((ks * 32 + l4 * 8) << 1);
                byte ^= (row & 7) << 4;
                bfr[fn][ks] = *(const bf16x8*)(lBb + byte);
            }
        f32x4 acc[2][4] = {};
#pragma unroll
        for (int ks = 0; ks < 2; ++ks)
#pragma unroll
            for (int fm = 0; fm < 2; ++fm)
#pragma unroll
                for (int fn = 0; fn < 4; ++fn)
                    acc[fm][fn] = __builtin_amdgcn_mfma_f32_16x16x32_bf16(
                        qa[fm][ks], bfr[fn][ks], acc[fm][fn], 0, 0, 0);

        const float* bias = (t == 0) ? qb : (t == 1) ? kb : vb;
#pragma unroll
        for (int fm = 0; fm < 2; ++fm)
#pragma unroll
            for (int fn = 0; fn < 4; ++fn)
#pragma unroll
                for (int r = 0; r < 4; ++r) {
                    const int srow = blockIdx.x * 128 + wave * 32 + fm * 16 + l4 * 4 + r;
                    const int e = fn * 16 + l15;
                    float v = acc[fm][fn][r] + bias[hd * HDIM + e];
                    if (t == 0) {
                        qh[((long)z * SEQ + srow) * HDIM + e] = __float2bfloat16(v * 0.125f);
                    } else if (t == 1) {
                        kh[((long)z * SEQ + srow) * HDIM + e] = __float2bfloat16(v);
                    } else {
                        vt[((long)z * HDIM + e) * SEQ + srow] = __float2bfloat16(v);
                    }
                }
    }
}

// ---------------------------------------------------------------------------
// Flash attention (known-good): per block one (b,hd) head and 64 q-rows;
// loop over 8 kv-tiles of 64 keys. grid (SEQ/64=8, B*H). h += O/l.
// ---------------------------------------------------------------------------
__global__ __launch_bounds__(256) void k_flash(const bf16* __restrict__ qh,
                                               const bf16* __restrict__ kh,
                                               const bf16* __restrict__ vt,
                                               float* __restrict__ h)
{
    __shared__ __align__(16) char lmem[24576];
    bf16* lQ = (bf16*)lmem;
    char* lKb = lmem + 8192;
    char* lVb = lmem + 16384;

    const int tid = threadIdx.x;
    const int lane = tid & 63, wave = tid >> 6;
    const int l15 = lane & 15, l4 = lane >> 4;
    const int z = blockIdx.y;
    const int b = z >> 4, hd = z & 15;
    const int q0 = blockIdx.x * 64;

    const bf16* Qsrc = qh + ((long)z * SEQ + q0) * HDIM;
#pragma unroll
    for (int it = 0; it < 2; ++it) {
        const int f = (it * 256 + tid) * 8;
        gload16(Qsrc + f, lQ + f);
    }
    __syncthreads();

    bf16x8 qa[2];
#pragma unroll
    for (int ks = 0; ks < 2; ++ks)
        qa[ks] = *(const bf16x8*)(lQ + (wave * 16 + l15) * 64 + ks * 32 + l4 * 8);

    char* lPb = lmem + wave * 2048;   // wave-private, aliases its own lQ rows

    f32x4 O[4] = {};
    float mrun[4], lrun[4];
#pragma unroll
    for (int r = 0; r < 4; ++r) { mrun[r] = -1e30f; lrun[r] = 0.0f; }

    for (int kv = 0; kv < SEQ / 64; ++kv) {
        __syncthreads();
        const bf16* Ksrc = kh + ((long)z * SEQ + kv * 64) * HDIM;
#pragma unroll
        for (int it = 0; it < 2; ++it) {
            const int f = (it * 256 + tid) * 8;
            const int r = f >> 6;
            const uint4 v = *(const uint4*)(Ksrc + f);
            *(uint4*)(lKb + ((f << 1) ^ ((r & 7) << 4))) = v;
        }
        const bf16* Vsrc = vt + (long)z * HDIM * SEQ + kv * 64;
#pragma unroll
        for (int it = 0; it < 2; ++it) {
            const int f = (it * 256 + tid) * 8;
            const int r = f >> 6, c = f & 63;
            const uint4 v = *(const uint4*)(Vsrc + (long)r * SEQ + c);
            *(uint4*)(lVb + ((f << 1) ^ ((r & 7) << 4))) = v;
        }
        __syncthreads();

        f32x4 sa[4];
#pragma unroll
        for (int fn = 0; fn < 4; ++fn) sa[fn] = (f32x4){0.f, 0.f, 0.f, 0.f};
#pragma unroll
        for (int ks = 0; ks < 2; ++ks)
#pragma unroll
            for (int fn = 0; fn < 4; ++fn) {
                const int row = fn * 16 + l15;
                int byte = (row << 7) + ((ks * 32 + l4 * 8) << 1);
                byte ^= (row & 7) << 4;
                const bf16x8 kb_ = *(const bf16x8*)(lKb + byte);
                sa[fn] = __builtin_amdgcn_mfma_f32_16x16x32_bf16(qa[ks], kb_, sa[fn], 0, 0, 0);
            }

#pragma unroll
        for (int r = 0; r < 4; ++r) {
            float mx = fmaxf(fmaxf(sa[0][r], sa[1][r]), fmaxf(sa[2][r], sa[3][r]));
#pragma unroll
            for (int m_ = 1; m_ < 16; m_ <<= 1) mx = fmaxf(mx, __shfl_xor(mx, m_));
            const float nm = fmaxf(mrun[r], mx);
            const float al = __expf(mrun[r] - nm);
            mrun[r] = nm;
            float p0 = __expf(sa[0][r] - nm), p1 = __expf(sa[1][r] - nm);
            float p2 = __expf(sa[2][r] - nm), p3 = __expf(sa[3][r] - nm);
            float ps = p0 + p1 + p2 + p3;
#pragma unroll
            for (int m_ = 1; m_ < 16; m_ <<= 1) ps += __shfl_xor(ps, m_);
            lrun[r] = lrun[r] * al + ps;
#pragma unroll
            for (int fn = 0; fn < 4; ++fn) O[fn][r] *= al;
            const int row = l4 * 4 + r;
            const int rsw = (row & 7) << 4;
            const int rb = row << 7;
            *(u16*)(lPb + ((rb + ((0 * 16 + l15) << 1)) ^ rsw)) = f2bu(p0);
            *(u16*)(lPb + ((rb + ((1 * 16 + l15) << 1)) ^ rsw)) = f2bu(p1);
            *(u16*)(lPb + ((rb + ((2 * 16 + l15) << 1)) ^ rsw)) = f2bu(p2);
            *(u16*)(lPb + ((rb + ((3 * 16 + l15) << 1)) ^ rsw)) = f2bu(p3);
        }

#pragma unroll
        for (int ks = 0; ks < 2; ++ks) {
            const int rowp = l15;
            int pbyte = (rowp << 7) + ((ks * 32 + l4 * 8) << 1);
            pbyte ^= (rowp & 7) << 4;
            const bf16x8 pa = *(const bf16x8*)(lPb + pbyte);
#pragma unroll
            for (int fn = 0; fn < 4; ++fn) {
                const int row = fn * 16 + l15;
                int byte = (row << 7) + ((ks * 32 + l4 * 8) << 1);
                byte ^= (row & 7) << 4;
                const bf16x8 vb_ = *(const bf16x8*)(lVb + byte);
                O[fn] = __builtin_amdgcn_mfma_f32_16x16x32_bf16(pa, vb_, O[fn], 0, 0, 0);
            }
        }
    }

    float rinv[4];
#pragma unroll
    for (int r = 0; r < 4; ++r) rinv[r] = 1.0f / lrun[r];
#pragma unroll
    for (int fn = 0; fn < 4; ++fn)
#pragma unroll
        for (int r = 0; r < 4; ++r) {
            const int srow = q0 + wave * 16 + l4 * 4 + r;
            const int e = fn * 16 + l15;
            h[((long)b * SEQ + srow) * DMODEL + hd * HDIM + e] += O[fn][r] * rinv[r];
        }
}

// ---------------------------------------------------------------------------
// MLP GEMM1 (pipelined): ff1 = gelu(z @ w1t^T + b1). grid (8, 32), 512 thr.
// XCD-chunked swizzle: each XCD owns 4 consecutive B-panels.
// ---------------------------------------------------------------------------
__global__ __launch_bounds__(512, 2) void k_gemm1(const bf16* __restrict__ zb,
                                                  const bf16* __restrict__ w1t,
                                                  const float* __restrict__ b1,
                                                  bf16* __restrict__ ff1)
{
    __shared__ __align__(16) char lmem[98304];
    // hw XCD = blockIdx.x (x fastest, grid.x=8). Decode so same-XCD blocks
    // share B-panels: by' = bx_hw*4 + (by_hw&3), bx' = by_hw>>2. Bijective.
    const int bx = (int)blockIdx.y >> 2;
    const int by = (int)blockIdx.x * 4 + ((int)blockIdx.y & 3);
    const bf16* A = zb + (long)bx * 256 * DMODEL;
    const bf16* B = w1t + (long)by * 128 * DMODEL;
    f32x4 acc[8][2] = {};
    gemm_pipe(A, DMODEL, B, DMODEL, DMODEL / 64, acc, lmem, lmem + 65536);

    const int lane = threadIdx.x & 63, wave = threadIdx.x >> 6;
    const int wr = wave >> 2, wc = wave & 3;
    const int l15 = lane & 15, l4 = lane >> 4;
#pragma unroll
    for (int fm = 0; fm < 8; ++fm)
#pragma unroll
        for (int fn = 0; fn < 2; ++fn)
#pragma unroll
            for (int r = 0; r < 4; ++r) {
                const int row = bx * 256 + wr * 128 + fm * 16 + l4 * 4 + r;
                const int col = by * 128 + wc * 32 + fn * 16 + l15;
                const float x = acc[fm][fn][r] + b1[col];
                const float g = 0.5f * x * (1.0f + erff(x * 0.70710678118f));
                ff1[(long)row * FFDIM + col] = __float2bfloat16(g);
            }
}

// ---------------------------------------------------------------------------
// MLP GEMM2 (pipelined, split-K=4): part[sk] = ff1[:,sk] @ w2t[:,sk]^T.
// grid (8, 8, 4), 512 threads. part is bf16. Swizzle: bx'<->by' swap so each
// XCD owns a single w2t row-panel.
// ---------------------------------------------------------------------------
__global__ __launch_bounds__(512, 2) void k_gemm2(const bf16* __restrict__ ff1,
                                                  const bf16* __restrict__ w2t,
                                                  bf16* __restrict__ part)
{
    __shared__ __align__(16) char lmem[98304];
    const int sk = blockIdx.z;
    const int bx = (int)blockIdx.y;     // swap: hw XCD = blockIdx.x = by'
    const int by = (int)blockIdx.x;
    const bf16* A = ff1 + (long)bx * 256 * FFDIM + (long)sk * 1024;
    const bf16* B = w2t + (long)by * 128 * FFDIM + (long)sk * 1024;
    f32x4 acc[8][2] = {};
    gemm_pipe(A, FFDIM, B, FFDIM, 1024 / 64, acc, lmem, lmem + 65536);

    bf16* out = part + (long)sk * (NB * SEQ) * DMODEL;
    const int lane = threadIdx.x & 63, wave = threadIdx.x >> 6;
    const int wr = wave >> 2, wc = wave & 3;
    const int l15 = lane & 15, l4 = lane >> 4;
#pragma unroll
    for (int fm = 0; fm < 8; ++fm)
#pragma unroll
        for (int fn = 0; fn < 2; ++fn)
#pragma unroll
            for (int r = 0; r < 4; ++r) {
                const int row = bx * 256 + wr * 128 + fm * 16 + l4 * 4 + r;
                const int col = by * 128 + wc * 32 + fn * 16 + l15;
                out[(long)row * DMODEL + col] = __float2bfloat16(acc[fm][fn][r]);
            }
}

// ---------------------------------------------------------------------------
// Fused: h += sum_k part[k] (bf16) + b2, then optionally y = LN(h) with
// next layer's ln1 params. One block per row (2048 blocks).
// ---------------------------------------------------------------------------
__global__ __launch_bounds__(256) void k_red2ln(const bf16* __restrict__ part,
                                                const float* __restrict__ b2,
                                                float* __restrict__ h,
                                                const float* __restrict__ lnw,
                                                const float* __restrict__ lnb,
                                                bf16* __restrict__ y,
                                                int do_ln)
{
    constexpr long NELT = (long)NB * SEQ * DMODEL;   // elements per split
    const long row = blockIdx.x;
    const int tid = threadIdx.x;
    const long e0 = row * DMODEL + tid * 4;          // 4 elements per thread
    float sum[4] = {0.f, 0.f, 0.f, 0.f};
#pragma unroll
    for (int sk = 0; sk < 4; ++sk) {
        const uint2 u = *(const uint2*)(part + sk * NELT + e0);
        sum[0] += bu2f((u16)(u.x & 0xffffu));
        sum[1] += bu2f((u16)(u.x >> 16));
        sum[2] += bu2f((u16)(u.y & 0xffffu));
        sum[3] += bu2f((u16)(u.y >> 16));
    }
    const float4 bv = ((const float4*)b2)[tid];
    float4 hv = ((float4*)h)[row * (DMODEL / 4) + tid];
    hv.x += sum[0] + bv.x;
    hv.y += sum[1] + bv.y;
    hv.z += sum[2] + bv.z;
    hv.w += sum[3] + bv.w;
    ((float4*)h)[row * (DMODEL / 4) + tid] = hv;

    if (!do_ln) return;
    float ss  = hv.x + hv.y + hv.z + hv.w;
    float ss2 = hv.x * hv.x + hv.y * hv.y + hv.z * hv.z + hv.w * hv.w;
#pragma unroll
    for (int off = 32; off; off >>= 1) { ss += __shfl_xor(ss, off); ss2 += __shfl_xor(ss2, off); }
    __shared__ float rs[4], rs2[4];
    const int wave = tid >> 6;
    if ((tid & 63) == 0) { rs[wave] = ss; rs2[wave] = ss2; }
    __syncthreads();
    const float S1 = rs[0] + rs[1] + rs[2] + rs[3];
    const float S2 = rs2[0] + rs2[1] + rs2[2] + rs2[3];
    const float mean = S1 * (1.0f / DMODEL);
    const float var  = S2 * (1.0f / DMODEL) - mean * mean;
    const float rstd = rsqrtf(var + 1e-5f);
    const float4 wv = ((const float4*)lnw)[tid];
    const float4 lb = ((const float4*)lnb)[tid];
    uint2 o;
    o.x = (u32)f2bu((hv.x - mean) * rstd * wv.x + lb.x) |
          ((u32)f2bu((hv.y - mean) * rstd * wv.y + lb.y) << 16);
    o.y = (u32)f2bu((hv.z - mean) * rstd * wv.z + lb.z) |
          ((u32)f2bu((hv.w - mean) * rstd * wv.w + lb.w) << 16);
    ((uint2*)(y + row * DMODEL))[tid] = o;
}

// ---------------------------------------------------------------------------
extern "C" void kernel_launch(void* const* d_in, const int* in_sizes, int n_in,
                              void* d_out, int out_size, void* d_ws, size_t ws_size,
                              hipStream_t stream)
{
    const float* x    = (const float*)d_in[0];
    const float* ln1w = (const float*)d_in[1];
    const float* ln1b = (const float*)d_in[2];
    const float* qw   = (const float*)d_in[3];
    const float* qb   = (const float*)d_in[4];
    const float* kw   = (const float*)d_in[5];
    const float* kb   = (const float*)d_in[6];
    const float* vw   = (const float*)d_in[7];
    const float* vb   = (const float*)d_in[8];
    const float* ln2w = (const float*)d_in[9];
    const float* ln2b = (const float*)d_in[10];
    const float* w1   = (const float*)d_in[11];
    const float* b1   = (const float*)d_in[12];
    const float* w2   = (const float*)d_in[13];
    const float* b2   = (const float*)d_in[14];

    char* ws = (char*)d_ws;
    const size_t MB = 1024 * 1024;
    bf16* y    = (bf16*)(ws + 0 * MB);     // [2048,1024] bf16 : 4MB
    bf16* zb   = (bf16*)(ws + 4 * MB);     // [2048,1024] bf16 : 4MB
    bf16* qh   = (bf16*)(ws + 8 * MB);     // [B*H,512,64]     : 4MB
    bf16* kh   = (bf16*)(ws + 12 * MB);    // [B*H,512,64]     : 4MB
    bf16* vt   = (bf16*)(ws + 16 * MB);    // [B*H,64,512]     : 4MB
    bf16* ff1  = (bf16*)(ws + 20 * MB);    // [2048,4096]      : 16MB
    bf16* part = (bf16*)(ws + 36 * MB);    // [4,2048,1024] bf16: 16MB
    bf16* w1tA = (bf16*)(ws + 68 * MB);    // [8][4096,1024]   : 64MB
    bf16* w2tA = (bf16*)(ws + 132 * MB);   // [8][1024,4096]   : 64MB

    float* h = (float*)d_out;

    // all-layer weight transpose, once
    k_transw_all<<<NLAYER * 2048, 256, 0, stream>>>(w1, w2, w1tA, w2tA);
    // initial LN1 for layer 0 (reads x, also writes h = x)
    k_ln<<<NB * SEQ, 256, 0, stream>>>(x, ln1w, ln1b, y, h);

    for (int l = 0; l < NLAYER; ++l) {
        const long wofs = (long)l * DMODEL * FFDIM;
        k_qkv2<<<dim3(4, NB * NHEAD), 256, 0, stream>>>(
            y, qw + (long)l * 65536, kw + (long)l * 65536, vw + (long)l * 65536,
            qb + l * NHEAD * HDIM, kb + l * NHEAD * HDIM, vb + l * NHEAD * HDIM,
            qh, kh, vt);
        k_flash<<<dim3(SEQ / 64, NB * NHEAD), 256, 0, stream>>>(qh, kh, vt, h);
        k_ln<<<NB * SEQ, 256, 0, stream>>>(h, ln2w + l * DMODEL, ln2b + l * DMODEL, zb,
                                           nullptr);
        k_gemm1<<<dim3(8, 32), 512, 0, stream>>>(zb, w1tA + wofs, b1 + l * FFDIM, ff1);
        k_gemm2<<<dim3(8, 8, 4), 512, 0, stream>>>(ff1, w2tA + wofs, part);
        const int last = (l == NLAYER - 1);
        k_red2ln<<<NB * SEQ, 256, 0, stream>>>(part, b2 + l * DMODEL, h,
                                               ln1w + (l + 1) * DMODEL * (1 - last),
                                               ln1b + (l + 1) * DMODEL * (1 - last),
                                               y, !last);
    }
}

// Round 11
// 926.599 us; speedup vs baseline: 1.0709x; 1.0709x over previous
//
#include <hip/hip_runtime.h>
#include <hip/hip_bf16.h>

typedef __hip_bfloat16 bf16;
typedef __bf16 bf16x8 __attribute__((ext_vector_type(8)));
typedef float f32x4 __attribute__((ext_vector_type(4)));
typedef unsigned short u16;
typedef unsigned int u32;

#define SEQ 512
#define DMODEL 1024
#define FFDIM 4096
#define NHEAD 16
#define HDIM 64
#define NB 4
#define NLAYER 8

#define SBAR() asm volatile("s_barrier" ::: "memory")

__device__ __forceinline__ u16 f2bu(float f) {
    union { bf16 h; u16 u; } c; c.h = __float2bfloat16(f); return c.u;
}
__device__ __forceinline__ float bu2f(u16 u) {
    union { u32 i; float f; } c; c.i = ((u32)u) << 16; return c.f;
}

// async global->LDS, 16B per lane. LDS dest must be linear in lane order.
__device__ __forceinline__ void gload16(const bf16* g, bf16* l) {
    __builtin_amdgcn_global_load_lds(
        (const __attribute__((address_space(1))) unsigned int*)g,
        (__attribute__((address_space(3))) unsigned int*)l,
        16, 0, 0);
}

// ---------------------------------------------------------------------------
// Deep-pipelined NT GEMM core (r8 quadrant structure): 256x128 tile, BK=64,
// 512 threads (8 waves 2Mx4N). Double-buffered LDS, counted vmcnt(6).
// A: row-major global, st_16x32 swizzle via inverse-swizzled source.
// B: TILED global layout — each K-tile is a linear 8192-bf16 blob whose
// internal order IS the desired LDS image (swizzle pre-baked by k_tilew).
// ---------------------------------------------------------------------------
__device__ __forceinline__ void gemm_pipe(
    const bf16* __restrict__ A, int lda,
    const bf16* __restrict__ Bt,       // tiled B: + t*8192 per K-tile
    int nkt,
    f32x4 (&acc)[8][2],
    char* lA, char* lB)                // lA: 2 x 32KB, lB: 2 x 16KB
{
    const int tid = threadIdx.x;
    const int lane = tid & 63;
    const int wave = tid >> 6;
    const int wr = wave >> 2, wc = wave & 3;
    const int l15 = lane & 15, l4 = lane >> 4;

    auto stage = [&](int c, int t) {
        const bf16* Ak = A + t * 64;
        bf16* dA = (bf16*)(lA + c * 32768);
        bf16* dB = (bf16*)(lB + c * 16384);
#pragma unroll
        for (int it = 0; it < 4; ++it) {
            const int e = (it * 512 + tid) * 8;
            const int r = e >> 6;
            const int cb = (e & 63) * 2;
            const int sc = (cb ^ (((r >> 2) & 1) << 5)) >> 1;
            gload16(Ak + (long)r * lda + sc, dA + e);
        }
        const bf16* Bk = Bt + (long)t * 8192;
#pragma unroll
        for (int it = 0; it < 2; ++it) {
            const int e = (it * 512 + tid) * 8;
            gload16(Bk + e, dB + e);
        }
    };

    stage(0, 0);
    stage(1, 1);
    asm volatile("s_waitcnt vmcnt(6)" ::: "memory");
    SBAR();

    for (int t = 0; t < nkt; ++t) {
        const int cur = t & 1;
        const char* bA = lA + cur * 32768;
        const char* bB = lB + cur * 16384;

        bf16x8 bf_[2][2];
#pragma unroll
        for (int fn = 0; fn < 2; ++fn)
#pragma unroll
            for (int ks = 0; ks < 2; ++ks) {
                const int row = wc * 32 + fn * 16 + l15;
                int byte = row * 128 + (ks * 32 + l4 * 8) * 2;
                byte ^= ((row >> 2) & 1) << 5;
                bf_[fn][ks] = *(const bf16x8*)(bB + byte);
            }
#pragma unroll
        for (int q = 0; q < 4; ++q) {
            bf16x8 af[2][2];
#pragma unroll
            for (int i = 0; i < 2; ++i)
#pragma unroll
                for (int ks = 0; ks < 2; ++ks) {
                    const int row = wr * 128 + (q * 2 + i) * 16 + l15;
                    int byte = row * 128 + (ks * 32 + l4 * 8) * 2;
                    byte ^= ((row >> 2) & 1) << 5;
                    af[i][ks] = *(const bf16x8*)(bA + byte);
                }
            __builtin_amdgcn_s_setprio(1);
#pragma unroll
            for (int i = 0; i < 2; ++i)
#pragma unroll
                for (int fn = 0; fn < 2; ++fn)
#pragma unroll
                    for (int ks = 0; ks < 2; ++ks)
                        acc[q * 2 + i][fn] = __builtin_amdgcn_mfma_f32_16x16x32_bf16(
                            af[i][ks], bf_[fn][ks], acc[q * 2 + i][fn], 0, 0, 0);
            __builtin_amdgcn_s_setprio(0);
        }
        SBAR();
        if (t + 2 < nkt) {
            stage(cur, t + 2);
            asm volatile("s_waitcnt vmcnt(6)" ::: "memory");
        } else {
            asm volatile("s_waitcnt vmcnt(0)" ::: "memory");
        }
        SBAR();
    }
}

// ---------------------------------------------------------------------------
// LayerNorm: in (fp32, row of 1024) -> out bf16; optional passthrough copy
// of the input row to hcopy (fuses the h=x init).
// ---------------------------------------------------------------------------
__global__ __launch_bounds__(256) void k_ln(const float* __restrict__ h,
                                            const float* __restrict__ w,
                                            const float* __restrict__ bp,
                                            bf16* __restrict__ out,
                                            float* __restrict__ hcopy)
{
    const int row = blockIdx.x;
    const int tid = threadIdx.x;
    const float4 x = ((const float4*)(h + (long)row * DMODEL))[tid];
    if (hcopy) ((float4*)(hcopy + (long)row * DMODEL))[tid] = x;
    float s  = x.x + x.y + x.z + x.w;
    float s2 = x.x * x.x + x.y * x.y + x.z * x.z + x.w * x.w;
#pragma unroll
    for (int off = 32; off; off >>= 1) { s += __shfl_xor(s, off); s2 += __shfl_xor(s2, off); }
    __shared__ float rs[4], rs2[4];
    const int wave = tid >> 6;
    if ((tid & 63) == 0) { rs[wave] = s; rs2[wave] = s2; }
    __syncthreads();
    const float S1 = rs[0] + rs[1] + rs[2] + rs[3];
    const float S2 = rs2[0] + rs2[1] + rs2[2] + rs2[3];
    const float mean = S1 * (1.0f / DMODEL);
    const float var  = S2 * (1.0f / DMODEL) - mean * mean;
    const float rstd = rsqrtf(var + 1e-5f);
    const float4 wv = ((const float4*)w)[tid];
    const float4 bv = ((const float4*)bp)[tid];
    uint2 o;
    o.x = (u32)f2bu((x.x - mean) * rstd * wv.x + bv.x) |
          ((u32)f2bu((x.y - mean) * rstd * wv.y + bv.y) << 16);
    o.y = (u32)f2bu((x.z - mean) * rstd * wv.z + bv.z) |
          ((u32)f2bu((x.w - mean) * rstd * wv.w + bv.w) << 16);
    ((uint2*)(out + (long)row * DMODEL))[tid] = o;
}

// ---------------------------------------------------------------------------
// Weight -> swizzled-tile converter. Each block builds ONE 128(n)x64(k) tile
// as a linear 16KB blob in the exact LDS-image order gemm_pipe expects:
//   T[e] = W[kt*64 + ksw][n0 + r],  r=e>>6, c=e&63, ksw = c ^ (((r>>2)&1)<<4)
// Writes are fully sequential; reads are 512B row spans.
// grid: NLAYER * (512 w1-tiles + 512 w2-tiles).
// ---------------------------------------------------------------------------
__global__ __launch_bounds__(256) void k_tilew(const float* __restrict__ w1,
                                               const float* __restrict__ w2,
                                               bf16* __restrict__ w1t,
                                               bf16* __restrict__ w2t)
{
    __shared__ u16 t[64][138];         // t[k][n], pad -> ~2-way banks both phases
    int bid = blockIdx.x;
    const int l = bid >> 10;
    bid &= 1023;
    const long lofs = (long)l * DMODEL * FFDIM;
    const float* src; bf16* dst; int ldsrc;
    if (bid < 512) {
        // w1 [D][FF] -> tiles for gemm1 (panels over FF, K over D)
        const int by = bid >> 4, kt = bid & 15;
        src = w1 + lofs + (long)(kt * 64) * FFDIM + by * 128;
        ldsrc = FFDIM;
        dst = w1t + lofs + ((long)by * 16 + kt) * 8192;
    } else {
        bid -= 512;
        // w2 [FF][D] -> tiles for gemm2 (panels over D, K over FF)
        const int by = bid >> 6, kt = bid & 63;
        src = w2 + lofs + (long)(kt * 64) * DMODEL + by * 128;
        ldsrc = DMODEL;
        dst = w2t + lofs + ((long)by * 64 + kt) * 8192;
    }
    const int tid = threadIdx.x;
    // phase 1: read 64 k-rows x 128 n (float4 per lane, 512B per row-group)
    const int n4 = (tid & 31) * 4;
    const int kr = tid >> 5;           // 0..7
#pragma unroll
    for (int j = 0; j < 8; ++j) {
        const int k = j * 8 + kr;
        const float4 v = *(const float4*)(src + (long)k * ldsrc + n4);
        t[k][n4]     = f2bu(v.x);
        t[k][n4 + 1] = f2bu(v.y);
        t[k][n4 + 2] = f2bu(v.z);
        t[k][n4 + 3] = f2bu(v.w);
    }
    __syncthreads();
    // phase 2: emit linear blob in swizzled order
#pragma unroll
    for (int it = 0; it < 4; ++it) {
        const int e0 = it * 2048 + tid * 8;
        const int r = e0 >> 6;                 // n-index 0..127
        const int c = e0 & 63;                 // k-group base (mult of 8)
        const int ksw = c ^ (((r >> 2) & 1) << 4);
        u16 v[8];
#pragma unroll
        for (int m = 0; m < 8; ++m) v[m] = t[ksw + m][r];
        uint4 o;
        o.x = (u32)v[0] | ((u32)v[1] << 16);
        o.y = (u32)v[2] | ((u32)v[3] << 16);
        o.z = (u32)v[4] | ((u32)v[5] << 16);
        o.w = (u32)v[6] | ((u32)v[7] << 16);
        *(uint4*)(dst + e0) = o;
    }
}

// ---------------------------------------------------------------------------
// Merged QKV with in-flight fp32->bf16 weight conversion. grid (4, B*H).
// q scaled 1/8; v stored transposed vt[e][s].
// ---------------------------------------------------------------------------
__global__ __launch_bounds__(256) void k_qkv2(const bf16* __restrict__ y,
                                              const float* __restrict__ qwl,
                                              const float* __restrict__ kwl,
                                              const float* __restrict__ vwl,
                                              const float* __restrict__ qb,
                                              const float* __restrict__ kb,
                                              const float* __restrict__ vb,
                                              bf16* __restrict__ qh,
                                              bf16* __restrict__ kh,
                                              bf16* __restrict__ vt)
{
    __shared__ __align__(16) char lmem[128 * 64 * 2 + 64 * 64 * 2];  // lA 16KB + lB 8KB
    bf16* lA = (bf16*)lmem;
    char* lBb = lmem + 128 * 64 * 2;

    const int tid = threadIdx.x;
    const int lane = tid & 63, wave = tid >> 6;
    const int l15 = lane & 15, l4 = lane >> 4;
    const int z = blockIdx.y;
    const int b = z >> 4, hd = z & 15;
    const bf16* A = y + (long)b * SEQ * DMODEL + hd * HDIM + (long)blockIdx.x * 128 * DMODEL;

#pragma unroll
    for (int it = 0; it < 4; ++it) {
        const int f = (it * 256 + tid) * 8;
        const int r = f >> 6, c = f & 63;
        gload16(A + (long)r * DMODEL + c, lA + f);
    }
    __syncthreads();

    bf16x8 qa[2][2];
#pragma unroll
    for (int fm = 0; fm < 2; ++fm)
#pragma unroll
        for (int ks = 0; ks < 2; ++ks)
            qa[fm][ks] = *(const bf16x8*)(lA + (wave * 32 + fm * 16 + l15) * 64 + ks * 32 + l4 * 8);

    for (int t = 0; t < 3; ++t) {
        __syncthreads();
        const float* Bsrc = ((t == 0) ? qwl : (t == 1) ? kwl : vwl) + (long)hd * HDIM * HDIM;
#pragma unroll
        for (int it = 0; it < 4; ++it) {
            const int f = (it * 256 + tid) * 4;
            const float4 v = *(const float4*)(Bsrc + f);
            uint2 o;
            o.x = (u32)f2bu(v.x) | ((u32)f2bu(v.y) << 16);
            o.y = (u32)f2bu(v.z) | ((u32)f2bu(v.w) << 16);
            const int row = f >> 6;
            const int byte = (f << 1) ^ ((row & 7) << 4);
            *(uint2*)(lBb + byte) = o;
        }
        __syncthreads();

        bf16x8 bfr[4][2];
#pragma unroll
        for (int fn = 0; fn < 4; ++fn)
#pragma unroll
            for (int ks = 0; ks < 2; ++ks) {
                const int row = fn * 16 + l15;
                int byte = (row << 7) + ((ks * 32 + l4 * 8) << 1);
                byte ^= (row & 7) << 4;
                bfr[fn][ks] = *(const bf16x8*)(lBb + byte);
            }
        f32x4 acc[2][4] = {};
#pragma unroll
        for (int ks = 0; ks < 2; ++ks)
#pragma unroll
            for (int fm = 0; fm < 2; ++fm)
#pragma unroll
                for (int fn = 0; fn < 4; ++fn)
                    acc[fm][fn] = __builtin_amdgcn_mfma_f32_16x16x32_bf16(
                        qa[fm][ks], bfr[fn][ks], acc[fm][fn], 0, 0, 0);

        const float* bias = (t == 0) ? qb : (t == 1) ? kb : vb;
#pragma unroll
        for (int fm = 0; fm < 2; ++fm)
#pragma unroll
            for (int fn = 0; fn < 4; ++fn)
#pragma unroll
                for (int r = 0; r < 4; ++r) {
                    const int srow = blockIdx.x * 128 + wave * 32 + fm * 16 + l4 * 4 + r;
                    const int e = fn * 16 + l15;
                    float v = acc[fm][fn][r] + bias[hd * HDIM + e];
                    if (t == 0) {
                        qh[((long)z * SEQ + srow) * HDIM + e] = __float2bfloat16(v * 0.125f);
                    } else if (t == 1) {
                        kh[((long)z * SEQ + srow) * HDIM + e] = __float2bfloat16(v);
                    } else {
                        vt[((long)z * HDIM + e) * SEQ + srow] = __float2bfloat16(v);
                    }
                }
    }
}

// ---------------------------------------------------------------------------
// Flash attention (known-good): per block one (b,hd) head and 64 q-rows;
// loop over 8 kv-tiles of 64 keys. grid (SEQ/64=8, B*H). h += O/l.
// ---------------------------------------------------------------------------
__global__ __launch_bounds__(256) void k_flash(const bf16* __restrict__ qh,
                                               const bf16* __restrict__ kh,
                                               const bf16* __restrict__ vt,
                                               float* __restrict__ h)
{
    __shared__ __align__(16) char lmem[24576];
    bf16* lQ = (bf16*)lmem;
    char* lKb = lmem + 8192;
    char* lVb = lmem + 16384;

    const int tid = threadIdx.x;
    const int lane = tid & 63, wave = tid >> 6;
    const int l15 = lane & 15, l4 = lane >> 4;
    const int z = blockIdx.y;
    const int b = z >> 4, hd = z & 15;
    const int q0 = blockIdx.x * 64;

    const bf16* Qsrc = qh + ((long)z * SEQ + q0) * HDIM;
#pragma unroll
    for (int it = 0; it < 2; ++it) {
        const int f = (it * 256 + tid) * 8;
        gload16(Qsrc + f, lQ + f);
    }
    __syncthreads();

    bf16x8 qa[2];
#pragma unroll
    for (int ks = 0; ks < 2; ++ks)
        qa[ks] = *(const bf16x8*)(lQ + (wave * 16 + l15) * 64 + ks * 32 + l4 * 8);

    char* lPb = lmem + wave * 2048;   // wave-private, aliases its own lQ rows

    f32x4 O[4] = {};
    float mrun[4], lrun[4];
#pragma unroll
    for (int r = 0; r < 4; ++r) { mrun[r] = -1e30f; lrun[r] = 0.0f; }

    for (int kv = 0; kv < SEQ / 64; ++kv) {
        __syncthreads();
        const bf16* Ksrc = kh + ((long)z * SEQ + kv * 64) * HDIM;
#pragma unroll
        for (int it = 0; it < 2; ++it) {
            const int f = (it * 256 + tid) * 8;
            const int r = f >> 6;
            const uint4 v = *(const uint4*)(Ksrc + f);
            *(uint4*)(lKb + ((f << 1) ^ ((r & 7) << 4))) = v;
        }
        const bf16* Vsrc = vt + (long)z * HDIM * SEQ + kv * 64;
#pragma unroll
        for (int it = 0; it < 2; ++it) {
            const int f = (it * 256 + tid) * 8;
            const int r = f >> 6, c = f & 63;
            const uint4 v = *(const uint4*)(Vsrc + (long)r * SEQ + c);
            *(uint4*)(lVb + ((f << 1) ^ ((r & 7) << 4))) = v;
        }
        __syncthreads();

        f32x4 sa[4];
#pragma unroll
        for (int fn = 0; fn < 4; ++fn) sa[fn] = (f32x4){0.f, 0.f, 0.f, 0.f};
#pragma unroll
        for (int ks = 0; ks < 2; ++ks)
#pragma unroll
            for (int fn = 0; fn < 4; ++fn) {
                const int row = fn * 16 + l15;
                int byte = (row << 7) + ((ks * 32 + l4 * 8) << 1);
                byte ^= (row & 7) << 4;
                const bf16x8 kb_ = *(const bf16x8*)(lKb + byte);
                sa[fn] = __builtin_amdgcn_mfma_f32_16x16x32_bf16(qa[ks], kb_, sa[fn], 0, 0, 0);
            }

#pragma unroll
        for (int r = 0; r < 4; ++r) {
            float mx = fmaxf(fmaxf(sa[0][r], sa[1][r]), fmaxf(sa[2][r], sa[3][r]));
#pragma unroll
            for (int m_ = 1; m_ < 16; m_ <<= 1) mx = fmaxf(mx, __shfl_xor(mx, m_));
            const float nm = fmaxf(mrun[r], mx);
            const float al = __expf(mrun[r] - nm);
            mrun[r] = nm;
            float p0 = __expf(sa[0][r] - nm), p1 = __expf(sa[1][r] - nm);
            float p2 = __expf(sa[2][r] - nm), p3 = __expf(sa[3][r] - nm);
            float ps = p0 + p1 + p2 + p3;
#pragma unroll
            for (int m_ = 1; m_ < 16; m_ <<= 1) ps += __shfl_xor(ps, m_);
            lrun[r] = lrun[r] * al + ps;
#pragma unroll
            for (int fn = 0; fn < 4; ++fn) O[fn][r] *= al;
            const int row = l4 * 4 + r;
            const int rsw = (row & 7) << 4;
            const int rb = row << 7;
            *(u16*)(lPb + ((rb + ((0 * 16 + l15) << 1)) ^ rsw)) = f2bu(p0);
            *(u16*)(lPb + ((rb + ((1 * 16 + l15) << 1)) ^ rsw)) = f2bu(p1);
            *(u16*)(lPb + ((rb + ((2 * 16 + l15) << 1)) ^ rsw)) = f2bu(p2);
            *(u16*)(lPb + ((rb + ((3 * 16 + l15) << 1)) ^ rsw)) = f2bu(p3);
        }

#pragma unroll
        for (int ks = 0; ks < 2; ++ks) {
            const int rowp = l15;
            int pbyte = (rowp << 7) + ((ks * 32 + l4 * 8) << 1);
            pbyte ^= (rowp & 7) << 4;
            const bf16x8 pa = *(const bf16x8*)(lPb + pbyte);
#pragma unroll
            for (int fn = 0; fn < 4; ++fn) {
                const int row = fn * 16 + l15;
                int byte = (row << 7) + ((ks * 32 + l4 * 8) << 1);
                byte ^= (row & 7) << 4;
                const bf16x8 vb_ = *(const bf16x8*)(lVb + byte);
                O[fn] = __builtin_amdgcn_mfma_f32_16x16x32_bf16(pa, vb_, O[fn], 0, 0, 0);
            }
        }
    }

    float rinv[4];
#pragma unroll
    for (int r = 0; r < 4; ++r) rinv[r] = 1.0f / lrun[r];
#pragma unroll
    for (int fn = 0; fn < 4; ++fn)
#pragma unroll
        for (int r = 0; r < 4; ++r) {
            const int srow = q0 + wave * 16 + l4 * 4 + r;
            const int e = fn * 16 + l15;
            h[((long)b * SEQ + srow) * DMODEL + hd * HDIM + e] += O[fn][r] * rinv[r];
        }
}

// ---------------------------------------------------------------------------
// MLP GEMM1 (pipelined, tiled B): ff1 = gelu(z @ w1t^T + b1). grid (8, 32).
// XCD-chunked swizzle: each XCD owns 4 consecutive B-panels.
// ---------------------------------------------------------------------------
__global__ __launch_bounds__(512, 2) void k_gemm1(const bf16* __restrict__ zb,
                                                  const bf16* __restrict__ w1t,
                                                  const float* __restrict__ b1,
                                                  bf16* __restrict__ ff1)
{
    __shared__ __align__(16) char lmem[98304];
    const int bx = (int)blockIdx.y >> 2;
    const int by = (int)blockIdx.x * 4 + ((int)blockIdx.y & 3);
    const bf16* A = zb + (long)bx * 256 * DMODEL;
    const bf16* Bt = w1t + (long)by * 16 * 8192;   // 16 K-tiles per panel
    f32x4 acc[8][2] = {};
    gemm_pipe(A, DMODEL, Bt, DMODEL / 64, acc, lmem, lmem + 65536);

    const int lane = threadIdx.x & 63, wave = threadIdx.x >> 6;
    const int wr = wave >> 2, wc = wave & 3;
    const int l15 = lane & 15, l4 = lane >> 4;
#pragma unroll
    for (int fm = 0; fm < 8; ++fm)
#pragma unroll
        for (int fn = 0; fn < 2; ++fn)
#pragma unroll
            for (int r = 0; r < 4; ++r) {
                const int row = bx * 256 + wr * 128 + fm * 16 + l4 * 4 + r;
                const int col = by * 128 + wc * 32 + fn * 16 + l15;
                const float x = acc[fm][fn][r] + b1[col];
                const float g = 0.5f * x * (1.0f + erff(x * 0.70710678118f));
                ff1[(long)row * FFDIM + col] = __float2bfloat16(g);
            }
}

// ---------------------------------------------------------------------------
// MLP GEMM2 (pipelined, tiled B, split-K=4): part[sk] (bf16). grid (8, 8, 4).
// ---------------------------------------------------------------------------
__global__ __launch_bounds__(512, 2) void k_gemm2(const bf16* __restrict__ ff1,
                                                  const bf16* __restrict__ w2t,
                                                  bf16* __restrict__ part)
{
    __shared__ __align__(16) char lmem[98304];
    const int sk = blockIdx.z;
    const int bx = (int)blockIdx.y;     // swap: hw XCD owns one w2t row-panel
    const int by = (int)blockIdx.x;
    const bf16* A = ff1 + (long)bx * 256 * FFDIM + (long)sk * 1024;
    const bf16* Bt = w2t + ((long)by * 64 + sk * 16) * 8192;   // 64 K-tiles/panel
    f32x4 acc[8][2] = {};
    gemm_pipe(A, FFDIM, Bt, 1024 / 64, acc, lmem, lmem + 65536);

    bf16* out = part + (long)sk * (NB * SEQ) * DMODEL;
    const int lane = threadIdx.x & 63, wave = threadIdx.x >> 6;
    const int wr = wave >> 2, wc = wave & 3;
    const int l15 = lane & 15, l4 = lane >> 4;
#pragma unroll
    for (int fm = 0; fm < 8; ++fm)
#pragma unroll
        for (int fn = 0; fn < 2; ++fn)
#pragma unroll
            for (int r = 0; r < 4; ++r) {
                const int row = bx * 256 + wr * 128 + fm * 16 + l4 * 4 + r;
                const int col = by * 128 + wc * 32 + fn * 16 + l15;
                out[(long)row * DMODEL + col] = __float2bfloat16(acc[fm][fn][r]);
            }
}

// ---------------------------------------------------------------------------
// Fused: h += sum_k part[k] (bf16) + b2, then optionally y = LN(h) with
// next layer's ln1 params. One block per row (2048 blocks).
// ---------------------------------------------------------------------------
__global__ __launch_bounds__(256) void k_red2ln(const bf16* __restrict__ part,
                                                const float* __restrict__ b2,
                                                float* __restrict__ h,
                                                const float* __restrict__ lnw,
                                                const float* __restrict__ lnb,
                                                bf16* __restrict__ y,
                                                int do_ln)
{
    constexpr long NELT = (long)NB * SEQ * DMODEL;   // elements per split
    const long row = blockIdx.x;
    const int tid = threadIdx.x;
    const long e0 = row * DMODEL + tid * 4;
    float sum[4] = {0.f, 0.f, 0.f, 0.f};
#pragma unroll
    for (int sk = 0; sk < 4; ++sk) {
        const uint2 u = *(const uint2*)(part + sk * NELT + e0);
        sum[0] += bu2f((u16)(u.x & 0xffffu));
        sum[1] += bu2f((u16)(u.x >> 16));
        sum[2] += bu2f((u16)(u.y & 0xffffu));
        sum[3] += bu2f((u16)(u.y >> 16));
    }
    const float4 bv = ((const float4*)b2)[tid];
    float4 hv = ((float4*)h)[row * (DMODEL / 4) + tid];
    hv.x += sum[0] + bv.x;
    hv.y += sum[1] + bv.y;
    hv.z += sum[2] + bv.z;
    hv.w += sum[3] + bv.w;
    ((float4*)h)[row * (DMODEL / 4) + tid] = hv;

    if (!do_ln) return;
    float ss  = hv.x + hv.y + hv.z + hv.w;
    float ss2 = hv.x * hv.x + hv.y * hv.y + hv.z * hv.z + hv.w * hv.w;
#pragma unroll
    for (int off = 32; off; off >>= 1) { ss += __shfl_xor(ss, off); ss2 += __shfl_xor(ss2, off); }
    __shared__ float rs[4], rs2[4];
    const int wave = tid >> 6;
    if ((tid & 63) == 0) { rs[wave] = ss; rs2[wave] = ss2; }
    __syncthreads();
    const float S1 = rs[0] + rs[1] + rs[2] + rs[3];
    const float S2 = rs2[0] + rs2[1] + rs2[2] + rs2[3];
    const float mean = S1 * (1.0f / DMODEL);
    const float var  = S2 * (1.0f / DMODEL) - mean * mean;
    const float rstd = rsqrtf(var + 1e-5f);
    const float4 wv = ((const float4*)lnw)[tid];
    const float4 lb = ((const float4*)lnb)[tid];
    uint2 o;
    o.x = (u32)f2bu((hv.x - mean) * rstd * wv.x + lb.x) |
          ((u32)f2bu((hv.y - mean) * rstd * wv.y + lb.y) << 16);
    o.y = (u32)f2bu((hv.z - mean) * rstd * wv.z + lb.z) |
          ((u32)f2bu((hv.w - mean) * rstd * wv.w + lb.w) << 16);
    ((uint2*)(y + row * DMODEL))[tid] = o;
}

// ---------------------------------------------------------------------------
extern "C" void kernel_launch(void* const* d_in, const int* in_sizes, int n_in,
                              void* d_out, int out_size, void* d_ws, size_t ws_size,
                              hipStream_t stream)
{
    const float* x    = (const float*)d_in[0];
    const float* ln1w = (const float*)d_in[1];
    const float* ln1b = (const float*)d_in[2];
    const float* qw   = (const float*)d_in[3];
    const float* qb   = (const float*)d_in[4];
    const float* kw   = (const float*)d_in[5];
    const float* kb   = (const float*)d_in[6];
    const float* vw   = (const float*)d_in[7];
    const float* vb   = (const float*)d_in[8];
    const float* ln2w = (const float*)d_in[9];
    const float* ln2b = (const float*)d_in[10];
    const float* w1   = (const float*)d_in[11];
    const float* b1   = (const float*)d_in[12];
    const float* w2   = (const float*)d_in[13];
    const float* b2   = (const float*)d_in[14];

    char* ws = (char*)d_ws;
    const size_t MB = 1024 * 1024;
    bf16* y    = (bf16*)(ws + 0 * MB);     // [2048,1024] bf16 : 4MB
    bf16* zb   = (bf16*)(ws + 4 * MB);     // [2048,1024] bf16 : 4MB
    bf16* qh   = (bf16*)(ws + 8 * MB);     // [B*H,512,64]     : 4MB
    bf16* kh   = (bf16*)(ws + 12 * MB);    // [B*H,512,64]     : 4MB
    bf16* vt   = (bf16*)(ws + 16 * MB);    // [B*H,64,512]     : 4MB
    bf16* ff1  = (bf16*)(ws + 20 * MB);    // [2048,4096]      : 16MB
    bf16* part = (bf16*)(ws + 36 * MB);    // [4,2048,1024] bf16: 16MB
    bf16* w1tA = (bf16*)(ws + 68 * MB);    // [8][32 panels][16 tiles][8192] : 64MB
    bf16* w2tA = (bf16*)(ws + 132 * MB);   // [8][8 panels][64 tiles][8192]  : 64MB

    float* h = (float*)d_out;

    // all-layer weight -> swizzled tiles, once
    k_tilew<<<NLAYER * 1024, 256, 0, stream>>>(w1, w2, w1tA, w2tA);
    // initial LN1 for layer 0 (reads x, also writes h = x)
    k_ln<<<NB * SEQ, 256, 0, stream>>>(x, ln1w, ln1b, y, h);

    for (int l = 0; l < NLAYER; ++l) {
        const long wofs = (long)l * DMODEL * FFDIM;
        k_qkv2<<<dim3(4, NB * NHEAD), 256, 0, stream>>>(
            y, qw + (long)l * 65536, kw + (long)l * 65536, vw + (long)l * 65536,
            qb + l * NHEAD * HDIM, kb + l * NHEAD * HDIM, vb + l * NHEAD * HDIM,
            qh, kh, vt);
        k_flash<<<dim3(SEQ / 64, NB * NHEAD), 256, 0, stream>>>(qh, kh, vt, h);
        k_ln<<<NB * SEQ, 256, 0, stream>>>(h, ln2w + l * DMODEL, ln2b + l * DMODEL, zb,
                                           nullptr);
        k_gemm1<<<dim3(8, 32), 512, 0, stream>>>(zb, w1tA + wofs, b1 + l * FFDIM, ff1);
        k_gemm2<<<dim3(8, 8, 4), 512, 0, stream>>>(ff1, w2tA + wofs, part);
        const int last = (l == NLAYER - 1);
        k_red2ln<<<NB * SEQ, 256, 0, stream>>>(part, b2 + l * DMODEL, h,
                                               ln1w + (l + 1) * DMODEL * (1 - last),
                                               ln1b + (l + 1) * DMODEL * (1 - last),
                                               y, !last);
    }
}